// Round 4
// baseline (96.135 us; speedup 1.0000x reference)
//
#include <hip/hip_runtime.h>

#define J_NUM 24
#define ELEMS 64               // batch elements per block
#define NTHREADS (ELEMS * 3)   // 192 threads = 3 waves; lane u -> (elem u/3, row u%3)
#define STRIDE 73              // padded floats per element in LDS (73*4B: odd -> conflict-free)

// SMPL kinematic tree (static)
__global__ __launch_bounds__(NTHREADS)
void fk_kernel(const float* __restrict__ pose, const float* __restrict__ trans,
               const float* __restrict__ Jm, float* __restrict__ out)
{
    __shared__ float s[ELEMS * STRIDE];   // 18688 B -> 8 blocks/CU fits in 160 KiB

    const int u = threadIdx.x;
    const size_t blockBase = (size_t)blockIdx.x * ELEMS;

    // ---- phase 1: coalesced global float4 pose loads -> padded LDS ----
    {
        const float4* src = reinterpret_cast<const float4*>(pose + blockBase * 72);
#pragma unroll
        for (int i = 0; i < 6; ++i) {
            int m = i * NTHREADS + u;        // float4 index 0..1151
            float4 v = src[m];
            int e = m / 18;
            int f = (m - e * 18) * 4;
            float* d = s + e * STRIDE + f;
            d[0] = v.x; d[1] = v.y; d[2] = v.z; d[3] = v.w;
        }
    }

    // trans[E*3 + r] == trans[blockBase*3 + u]: perfectly coalesced
    const float tr = trans[blockBase * 3 + u];

    __syncthreads();

    const int e = u / 3;          // local element 0..63
    const int r = u - e * 3;      // row 0..2
    const float* p = s + e * STRIDE;

    const int par[J_NUM] = {-1,0,0,0,1,2,3,4,5,6,7,8,9,9,9,12,13,14,16,17,18,19,20,21};

    // per-lane state: ROW r of each joint's composed rotation + component r of position
    float rcx[J_NUM], rcy[J_NUM], rcz[J_NUM];
    float pc[J_NUM];

#pragma unroll
    for (int j = 0; j < J_NUM; ++j) {
        // full local Rodrigues (recomputed in all 3 lanes of the group; same inputs -> LDS broadcast)
        float ax = p[j*3+0], ay = p[j*3+1], az = p[j*3+2];
        float tt = ax*ax + ay*ay + az*az + 1e-16f;
        float inv = rsqrtf(tt);
        float th = tt * inv;                 // sqrt(tt)
        float x = ax*inv, y = ay*inv, z = az*inv;
        float c = __cosf(th), sn = __sinf(th);
        float C = 1.0f - c;
        float cx = C*x, cy = C*y, cz = C*z;
        float sx = sn*x, sy = sn*y, sz = sn*z;
        float R0 = fmaf(cx, x, c);
        float R1 = fmaf(cx, y, -sz);
        float R2 = fmaf(cx, z,  sy);
        float R3 = fmaf(cy, x,  sz);
        float R4 = fmaf(cy, y, c);
        float R5 = fmaf(cy, z, -sx);
        float R6 = fmaf(cz, x, -sy);
        float R7 = fmaf(cz, y,  sx);
        float R8 = fmaf(cz, z, c);

        // rest-pose local offset (wave-uniform scalar loads)
        float ox = Jm[j*16 + 3];
        float oy = Jm[j*16 + 7];
        float oz = Jm[j*16 + 11];

        if (j == 0) {
            // pick row r of R_0 (few cndmasks, once)
            rcx[0] = (r == 0) ? R0 : ((r == 1) ? R3 : R6);
            rcy[0] = (r == 0) ? R1 : ((r == 1) ? R4 : R7);
            rcz[0] = (r == 0) ? R2 : ((r == 1) ? R5 : R8);
            pc[0]  = (r == 0) ? ox : ((r == 1) ? oy : oz);
        } else {
            const int q = par[j];
            float c0 = rcx[q], c1 = rcy[q], c2 = rcz[q];
            pc[j]  = pc[q] + c0*ox + c1*oy + c2*oz;
            rcx[j] = c0*R0 + c1*R3 + c2*R6;
            rcy[j] = c0*R1 + c1*R4 + c2*R7;
            rcz[j] = c0*R2 + c1*R5 + c2*R8;
        }
    }

    // all pose reads complete before overwriting the same LDS region with outputs
    __syncthreads();

    {
        float* w = s + e * STRIDE + r;
#pragma unroll
        for (int j = 0; j < J_NUM; ++j)
            w[j*3] = pc[j] + tr;     // s[e*73 + j*3 + r]
    }

    __syncthreads();

    // ---- phase 3: padded LDS -> dense coalesced global float4 stores ----
    {
        float4* dst = reinterpret_cast<float4*>(out + blockBase * 72);
#pragma unroll
        for (int i = 0; i < 6; ++i) {
            int m = i * NTHREADS + u;
            int e2 = m / 18;
            int f = (m - e2 * 18) * 4;
            const float* src = s + e2 * STRIDE + f;
            float4 v;
            v.x = src[0]; v.y = src[1]; v.z = src[2]; v.w = src[3];
            dst[m] = v;
        }
    }
}

extern "C" void kernel_launch(void* const* d_in, const int* in_sizes, int n_in,
                              void* d_out, int out_size, void* d_ws, size_t ws_size,
                              hipStream_t stream) {
    const float* pose  = (const float*)d_in[0];
    const float* trans = (const float*)d_in[1];
    const float* Jm    = (const float*)d_in[2];
    float* out = (float*)d_out;

    int B = in_sizes[0] / (J_NUM * 3);   // 131072
    int blocks = B / ELEMS;              // 2048
    fk_kernel<<<blocks, NTHREADS, 0, stream>>>(pose, trans, Jm, out);
}

// Round 5
// 94.329 us; speedup vs baseline: 1.0191x; 1.0191x over previous
//
#include <hip/hip_runtime.h>

#define J_NUM 24
#define BLOCK 64      // one wave per block; B = 131072 divisible by 64
#define STRIDE 76     // floats per element in LDS: 304 B -> every element 16B-aligned (b128-clean)

__global__ __launch_bounds__(BLOCK, 2)
void fk_kernel(const float* __restrict__ pose, const float* __restrict__ trans,
               const float* __restrict__ Jm, float* __restrict__ out)
{
    __shared__ __align__(16) float s[BLOCK * STRIDE];   // 19456 B -> 8 blocks/CU

    const int t = threadIdx.x;
    const size_t blockBase = (size_t)blockIdx.x * BLOCK;
    const size_t b = blockBase + t;

    // ---- direct per-thread pose loads: 18 x float4, 288 B thread stride.
    // R1 measured FETCH ~= 20 MB with this pattern: reads are cheap, no LDS needed.
    float p[72];
    {
        const float4* pp = reinterpret_cast<const float4*>(pose + b * 72);
#pragma unroll
        for (int i = 0; i < 18; ++i) {
            float4 v = pp[i];
            p[4*i+0] = v.x; p[4*i+1] = v.y; p[4*i+2] = v.z; p[4*i+3] = v.w;
        }
    }

    const float t0 = trans[b*3 + 0];
    const float t1 = trans[b*3 + 1];
    const float t2 = trans[b*3 + 2];

    const int par[J_NUM] = {-1,0,0,0,1,2,3,4,5,6,7,8,9,9,9,12,13,14,16,17,18,19,20,21};

    float Rc[J_NUM][9];
    float Pc[J_NUM][3];
    float o[72];          // outputs buffered in regs; flushed as b128 after the loop

#pragma unroll
    for (int j = 0; j < J_NUM; ++j) {
        float ax = p[j*3+0], ay = p[j*3+1], az = p[j*3+2];
        float tt = fmaf(ax, ax, fmaf(ay, ay, fmaf(az, az, 1e-16f)));
        float inv = rsqrtf(tt);          // v_rsq_f32
        float th  = tt * inv;            // sqrt(tt)
        float x = ax*inv, y = ay*inv, z = az*inv;
        float c = __cosf(th), sn = __sinf(th);
        float C = 1.0f - c;
        float cx = C*x, cy = C*y, cz = C*z;
        float sx = sn*x, sy = sn*y, sz = sn*z;
        float R0 = fmaf(cx, x, c);
        float R1 = fmaf(cx, y, -sz);
        float R2 = fmaf(cx, z,  sy);
        float R3 = fmaf(cy, x,  sz);
        float R4 = fmaf(cy, y, c);
        float R5 = fmaf(cy, z, -sx);
        float R6 = fmaf(cz, x, -sy);
        float R7 = fmaf(cz, y,  sx);
        float R8 = fmaf(cz, z, c);

        // rest-pose local offset (wave-uniform -> s_load, scalar cache)
        float ox = Jm[j*16 + 3];
        float oy = Jm[j*16 + 7];
        float oz = Jm[j*16 + 11];

        if (j == 0) {
            Rc[0][0]=R0; Rc[0][1]=R1; Rc[0][2]=R2;
            Rc[0][3]=R3; Rc[0][4]=R4; Rc[0][5]=R5;
            Rc[0][6]=R6; Rc[0][7]=R7; Rc[0][8]=R8;
            Pc[0][0]=ox; Pc[0][1]=oy; Pc[0][2]=oz;
        } else {
            const int q = par[j];
            Pc[j][0] = fmaf(Rc[q][0], ox, fmaf(Rc[q][1], oy, fmaf(Rc[q][2], oz, Pc[q][0])));
            Pc[j][1] = fmaf(Rc[q][3], ox, fmaf(Rc[q][4], oy, fmaf(Rc[q][5], oz, Pc[q][1])));
            Pc[j][2] = fmaf(Rc[q][6], ox, fmaf(Rc[q][7], oy, fmaf(Rc[q][8], oz, Pc[q][2])));
            Rc[j][0] = fmaf(Rc[q][0], R0, fmaf(Rc[q][1], R3, Rc[q][2]*R6));
            Rc[j][1] = fmaf(Rc[q][0], R1, fmaf(Rc[q][1], R4, Rc[q][2]*R7));
            Rc[j][2] = fmaf(Rc[q][0], R2, fmaf(Rc[q][1], R5, Rc[q][2]*R8));
            Rc[j][3] = fmaf(Rc[q][3], R0, fmaf(Rc[q][4], R3, Rc[q][5]*R6));
            Rc[j][4] = fmaf(Rc[q][3], R1, fmaf(Rc[q][4], R4, Rc[q][5]*R7));
            Rc[j][5] = fmaf(Rc[q][3], R2, fmaf(Rc[q][4], R5, Rc[q][5]*R8));
            Rc[j][6] = fmaf(Rc[q][6], R0, fmaf(Rc[q][7], R3, Rc[q][8]*R6));
            Rc[j][7] = fmaf(Rc[q][6], R1, fmaf(Rc[q][7], R4, Rc[q][8]*R7));
            Rc[j][8] = fmaf(Rc[q][6], R2, fmaf(Rc[q][7], R5, Rc[q][8]*R8));
        }

        o[j*3+0] = Pc[j][0] + t0;
        o[j*3+1] = Pc[j][1] + t1;
        o[j*3+2] = Pc[j][2] + t2;
    }

    // ---- phase 2: regs -> LDS, 18 x ds_write_b128 at 304 B element stride ----
    {
        float* mine = s + t * STRIDE;
#pragma unroll
        for (int k = 0; k < 18; ++k) {
            float4 v;
            v.x = o[4*k+0]; v.y = o[4*k+1]; v.z = o[4*k+2]; v.w = o[4*k+3];
            *reinterpret_cast<float4*>(mine + 4*k) = v;
        }
    }

    __syncthreads();

    // ---- phase 3: LDS (b128 reads) -> dense coalesced global float4 stores ----
    {
        float4* dst = reinterpret_cast<float4*>(out + blockBase * 72);
#pragma unroll
        for (int i = 0; i < 18; ++i) {
            int m = i * BLOCK + t;          // float4 index 0..1151
            int e = m / 18;                 // source element
            int f = (m - e * 18) * 4;       // float offset within element (mult of 4)
            float4 v = *reinterpret_cast<const float4*>(s + e * STRIDE + f);
            dst[m] = v;
        }
    }
}

extern "C" void kernel_launch(void* const* d_in, const int* in_sizes, int n_in,
                              void* d_out, int out_size, void* d_ws, size_t ws_size,
                              hipStream_t stream) {
    const float* pose  = (const float*)d_in[0];
    const float* trans = (const float*)d_in[1];
    const float* Jm    = (const float*)d_in[2];
    float* out = (float*)d_out;

    int B = in_sizes[0] / (J_NUM * 3);   // 131072
    int blocks = B / BLOCK;              // 2048
    fk_kernel<<<blocks, BLOCK, 0, stream>>>(pose, trans, Jm, out);
}

// Round 6
// 93.129 us; speedup vs baseline: 1.0323x; 1.0129x over previous
//
#include <hip/hip_runtime.h>

#define J_NUM 24
#define BLOCK 64        // one wave per block; barriers degenerate to s_waitcnt
#define PSTRIDE 73      // pose element stride in LDS (odd -> scalar reads conflict-free)
#define OSTRIDE 76      // output element stride (16B aligned -> b128, bank stride 19 -> free)
#define LDS_FLOATS (BLOCK * OSTRIDE)   // 19456 B -> 8 blocks/CU in 160 KiB

__global__ __launch_bounds__(BLOCK, 2)
void fk_kernel(const float* __restrict__ pose, const float* __restrict__ trans,
               const float* __restrict__ Jm, float* __restrict__ out)
{
    __shared__ __align__(16) float s[LDS_FLOATS];  // pose (stride 73), then outputs (stride 76)

    const int t = threadIdx.x;
    const size_t blockBase = (size_t)blockIdx.x * BLOCK;
    const size_t b = blockBase + t;

    // ---- phase 1: dense coalesced float4 global loads -> LDS at stride 73 ----
    {
        const float4* src = reinterpret_cast<const float4*>(pose + blockBase * 72);
#pragma unroll
        for (int i = 0; i < 18; ++i) {
            int m = i * BLOCK + t;          // float4 index 0..1151
            float4 v = src[m];
            int e = m / 18;
            int f = (m - e * 18) * 4;
            float* d = s + e * PSTRIDE + f;
            d[0] = v.x; d[1] = v.y; d[2] = v.z; d[3] = v.w;
        }
    }

    const float t0 = trans[b*3 + 0];
    const float t1 = trans[b*3 + 1];
    const float t2 = trans[b*3 + 2];

    __syncthreads();

    // this thread's pose: s[t*73 + 0..71]; scalar reads bank=(9t+c)%32 -> 2-way, free
    const float* p = s + t * PSTRIDE;

    const int par[J_NUM] = {-1,0,0,0,1,2,3,4,5,6,7,8,9,9,9,12,13,14,16,17,18,19,20,21};

    float Rc[J_NUM][9];   // SROA'd; live set ~5 matrices at peak
    float Pc[J_NUM][3];
    float o[72];          // outputs; peak pressure hits only at loop end when Rc is dead

#pragma unroll
    for (int j = 0; j < J_NUM; ++j) {
        float ax = p[j*3+0], ay = p[j*3+1], az = p[j*3+2];
        float tt = fmaf(ax, ax, fmaf(ay, ay, fmaf(az, az, 1e-16f)));
        float inv = rsqrtf(tt);
        float th  = tt * inv;               // sqrt(tt)
        float x = ax*inv, y = ay*inv, z = az*inv;
        float c = __cosf(th), sn = __sinf(th);
        float C = 1.0f - c;
        float cx = C*x, cy = C*y, cz = C*z;
        float sx = sn*x, sy = sn*y, sz = sn*z;
        float R0 = fmaf(cx, x, c);
        float R1 = fmaf(cx, y, -sz);
        float R2 = fmaf(cx, z,  sy);
        float R3 = fmaf(cy, x,  sz);
        float R4 = fmaf(cy, y, c);
        float R5 = fmaf(cy, z, -sx);
        float R6 = fmaf(cz, x, -sy);
        float R7 = fmaf(cz, y,  sx);
        float R8 = fmaf(cz, z, c);

        // rest-pose local offset (wave-uniform -> scalar loads)
        float ox = Jm[j*16 + 3];
        float oy = Jm[j*16 + 7];
        float oz = Jm[j*16 + 11];

        if (j == 0) {
            Rc[0][0]=R0; Rc[0][1]=R1; Rc[0][2]=R2;
            Rc[0][3]=R3; Rc[0][4]=R4; Rc[0][5]=R5;
            Rc[0][6]=R6; Rc[0][7]=R7; Rc[0][8]=R8;
            Pc[0][0]=ox; Pc[0][1]=oy; Pc[0][2]=oz;
        } else {
            const int q = par[j];
            Pc[j][0] = fmaf(Rc[q][0], ox, fmaf(Rc[q][1], oy, fmaf(Rc[q][2], oz, Pc[q][0])));
            Pc[j][1] = fmaf(Rc[q][3], ox, fmaf(Rc[q][4], oy, fmaf(Rc[q][5], oz, Pc[q][1])));
            Pc[j][2] = fmaf(Rc[q][6], ox, fmaf(Rc[q][7], oy, fmaf(Rc[q][8], oz, Pc[q][2])));
            Rc[j][0] = fmaf(Rc[q][0], R0, fmaf(Rc[q][1], R3, Rc[q][2]*R6));
            Rc[j][1] = fmaf(Rc[q][0], R1, fmaf(Rc[q][1], R4, Rc[q][2]*R7));
            Rc[j][2] = fmaf(Rc[q][0], R2, fmaf(Rc[q][1], R5, Rc[q][2]*R8));
            Rc[j][3] = fmaf(Rc[q][3], R0, fmaf(Rc[q][4], R3, Rc[q][5]*R6));
            Rc[j][4] = fmaf(Rc[q][3], R1, fmaf(Rc[q][4], R4, Rc[q][5]*R7));
            Rc[j][5] = fmaf(Rc[q][3], R2, fmaf(Rc[q][4], R5, Rc[q][5]*R8));
            Rc[j][6] = fmaf(Rc[q][6], R0, fmaf(Rc[q][7], R3, Rc[q][8]*R6));
            Rc[j][7] = fmaf(Rc[q][6], R1, fmaf(Rc[q][7], R4, Rc[q][8]*R7));
            Rc[j][8] = fmaf(Rc[q][6], R2, fmaf(Rc[q][7], R5, Rc[q][8]*R8));
        }

        o[j*3+0] = Pc[j][0] + t0;
        o[j*3+1] = Pc[j][1] + t1;
        o[j*3+2] = Pc[j][2] + t2;
    }

    // all pose reads done before the output region (different stride) overwrites them
    __syncthreads();

    // ---- phase 2: regs -> LDS, 18 x ds_write_b128 at stride 76 (bank stride 19: free) ----
    {
        float* mine = s + t * OSTRIDE;
#pragma unroll
        for (int k = 0; k < 18; ++k) {
            float4 v;
            v.x = o[4*k+0]; v.y = o[4*k+1]; v.z = o[4*k+2]; v.w = o[4*k+3];
            *reinterpret_cast<float4*>(mine + 4*k) = v;
        }
    }

    __syncthreads();

    // ---- phase 3: b128 LDS reads -> dense coalesced global float4 stores ----
    {
        float4* dst = reinterpret_cast<float4*>(out + blockBase * 72);
#pragma unroll
        for (int i = 0; i < 18; ++i) {
            int m = i * BLOCK + t;
            int e = m / 18;
            int f = (m - e * 18) * 4;
            float4 v = *reinterpret_cast<const float4*>(s + e * OSTRIDE + f);
            dst[m] = v;
        }
    }
}

extern "C" void kernel_launch(void* const* d_in, const int* in_sizes, int n_in,
                              void* d_out, int out_size, void* d_ws, size_t ws_size,
                              hipStream_t stream) {
    const float* pose  = (const float*)d_in[0];
    const float* trans = (const float*)d_in[1];
    const float* Jm    = (const float*)d_in[2];
    float* out = (float*)d_out;

    int B = in_sizes[0] / (J_NUM * 3);   // 131072
    int blocks = B / BLOCK;              // 2048
    fk_kernel<<<blocks, BLOCK, 0, stream>>>(pose, trans, Jm, out);
}